// Round 8
// baseline (289.368 us; speedup 1.0000x reference)
//
#include <hip/hip_runtime.h>
#include <hip/hip_bf16.h>
#include <stdint.h>

typedef __attribute__((ext_vector_type(8))) __bf16 bf16x8;
typedef __attribute__((ext_vector_type(4))) float f32x4;
typedef unsigned short u16;

#define N_NODES 51200
#define N_EDGES 819200
#define F_IN 400
#define K1PAD 416
#define H_DIM 256
#define C_OUT 2
#define N_GRAPHS 128
#define NODES_PER_GRAPH 400
#define NB_SCAN (N_NODES / 256)   // 200 blocks

__device__ __forceinline__ u16 f2bf(float f) {
  uint32_t u = __builtin_bit_cast(uint32_t, f);
  u = (u + 0x7fffu + ((u >> 16) & 1u)) >> 16;
  return (u16)u;
}
__device__ __forceinline__ float bf2f(u16 s) {
  uint32_t u = ((uint32_t)s) << 16;
  return __builtin_bit_cast(float, u);
}
__device__ __forceinline__ float bflo(uint32_t u) {
  return __builtin_bit_cast(float, u << 16);
}
__device__ __forceinline__ float bfhi(uint32_t u) {
  return __builtin_bit_cast(float, u & 0xffff0000u);
}

typedef const __attribute__((address_space(1))) unsigned int* gas_ptr;
typedef __attribute__((address_space(3))) unsigned int* las_ptr;
__device__ __forceinline__ void gl_lds16(const void* g, void* l) {
  __builtin_amdgcn_global_load_lds((gas_ptr)g, (las_ptr)l, 16, 0, 0);
}
__device__ __forceinline__ void wait_vm0()   { asm volatile("s_waitcnt vmcnt(0)" ::: "memory"); }
__device__ __forceinline__ void wait_vm4()   { asm volatile("s_waitcnt vmcnt(4)" ::: "memory"); }
__device__ __forceinline__ void wait_vm5()   { asm volatile("s_waitcnt vmcnt(5)" ::: "memory"); }
__device__ __forceinline__ void wait_vm6()   { asm volatile("s_waitcnt vmcnt(6)" ::: "memory"); }
__device__ __forceinline__ void wait_vm10()  { asm volatile("s_waitcnt vmcnt(10)" ::: "memory"); }
__device__ __forceinline__ void wait_lgkm0() { asm volatile("s_waitcnt lgkmcnt(0)" ::: "memory"); }

// ---------------- degree histogram (counts[d] = in-degree) ----------------
__global__ void k_hist(const int* __restrict__ dst, int* __restrict__ counts, int E) {
  int e = blockIdx.x * 256 + threadIdx.x;
  if (e < E) atomicAdd(&counts[dst[e]], 1);
}

// ---------------- hierarchical scan: phase 1, per-block sums --------------
__global__ __launch_bounds__(256) void k_reduce(const int* __restrict__ counts,
                                                int* __restrict__ bsum) {
  int i = blockIdx.x * 256 + threadIdx.x;
  int v = counts[i];
#pragma unroll
  for (int o = 32; o; o >>= 1) v += __shfl_xor(v, o);
  __shared__ int wsum[4];
  if ((threadIdx.x & 63) == 0) wsum[threadIdx.x >> 6] = v;
  __syncthreads();
  if (threadIdx.x == 0) bsum[blockIdx.x] = wsum[0] + wsum[1] + wsum[2] + wsum[3];
}

// ---------------- phase 2: scan the 200 block sums (one small block) ------
__global__ __launch_bounds__(256) void k_scantop(const int* __restrict__ bsum,
                                                 int* __restrict__ boff,
                                                 int* __restrict__ off_last) {
  __shared__ int s[256];
  int t = threadIdx.x;
  int v = (t < NB_SCAN) ? bsum[t] : 0;
  s[t] = v;
  __syncthreads();
  for (int d = 1; d < 256; d <<= 1) {
    int u = (t >= d) ? s[t - d] : 0;
    __syncthreads();
    s[t] += u;
    __syncthreads();
  }
  if (t < NB_SCAN) boff[t] = s[t] - v;   // exclusive prefix of block sums
  if (t == 0) *off_last = N_EDGES;       // off[N] = total edges
}

// ---------------- phase 3: local scan + block offset; also dis ------------
__global__ __launch_bounds__(256) void k_scanlocal(const int* __restrict__ counts,
                                                   const int* __restrict__ boff,
                                                   int* __restrict__ off,
                                                   int* __restrict__ cursor,
                                                   float* __restrict__ dis) {
  __shared__ int s[256];
  int t = threadIdx.x;
  int i = blockIdx.x * 256 + t;
  int v = counts[i];
  s[t] = v;
  __syncthreads();
  for (int d = 1; d < 256; d <<= 1) {
    int u = (t >= d) ? s[t - d] : 0;
    __syncthreads();
    s[t] += u;
    __syncthreads();
  }
  int ex = boff[blockIdx.x] + s[t] - v;
  off[i] = ex;
  cursor[i] = ex;
  dis[i] = rsqrtf(1.0f + (float)v);
}

// ---------------- scatter edges into CSR (sorted by dst) ------------------
__global__ void k_scatter(const int* __restrict__ src, const int* __restrict__ dst,
                          int* __restrict__ cursor, int* __restrict__ csr_src, int E) {
  int e = blockIdx.x * 256 + threadIdx.x;
  if (e < E) {
    int d = dst[e];
    int p = atomicAdd(&cursor[d], 1);
    csr_src[p] = src[e];
  }
}

// ------- transpose weights to bf16 [n][k], K1 padded to 416 with zeros ----
__global__ __launch_bounds__(256) void k_prepw(const float* __restrict__ W1,
                                               const float* __restrict__ W2,
                                               u16* __restrict__ W1T,
                                               u16* __restrict__ W2T) {
  int b = blockIdx.x, n = threadIdx.x;
  if (b < K1PAD) {
    int k = b;
    W1T[n * K1PAD + k] = (k < F_IN) ? f2bf(W1[k * H_DIM + n]) : (u16)0;
  } else {
    int k = b - K1PAD;
    W2T[n * H_DIM + k] = f2bf(W2[k * H_DIM + n]);
  }
}

// ---------------- layer-1 MFMA GEMM (fp32 A): 2-deep counted-vmcnt pipe ---
__global__ __launch_bounds__(256) void k_mmA(const float* __restrict__ Ap,
                                             const u16* __restrict__ BT,
                                             const float* __restrict__ dis,
                                             u16* __restrict__ C) {
  constexpr int K = F_IN, KB = K1PAD, NS = KB >> 5;   // NS = 13
  __shared__ __align__(16) u16 As[2][64 * 32];
  __shared__ __align__(16) u16 Bs[2][256 * 32];
  const int tid = threadIdx.x;
  const int lane = tid & 63, wid = tid >> 6;
  const int lr = lane & 15, lg = lane >> 4;
  const int m0 = blockIdx.x * 64;
  const int bRow = lane >> 2, bK8 = (lane & 3) << 3;
  const int aRow = tid >> 2, aK8 = (tid & 3) << 3;

  float4 p0a, p0b, p1a, p1b;

  auto issueB = [&](int s, int buf) {
    int k0 = s << 5;
#pragma unroll
    for (int j = 0; j < 4; ++j) {
      int c = wid * 4 + j;
      gl_lds16(BT + (size_t)(c * 16 + bRow) * KB + k0 + bK8, (char*)Bs[buf] + c * 1024);
    }
  };
  auto loadA = [&](int s, float4& fa, float4& fb) {
    int gk = (s << 5) + aK8;
    const float* p = Ap + (size_t)(m0 + aRow) * K + gk;
    if (gk < K) {
      fa = *reinterpret_cast<const float4*>(p);
      fb = *reinterpret_cast<const float4*>(p + 4);
    } else {
      fa = float4{0.f, 0.f, 0.f, 0.f};
      fb = float4{0.f, 0.f, 0.f, 0.f};
    }
  };
  auto writeA = [&](int buf, const float4& fa, const float4& fb) {
    alignas(16) u16 u[8];
    u[0] = f2bf(fa.x); u[1] = f2bf(fa.y); u[2] = f2bf(fa.z); u[3] = f2bf(fa.w);
    u[4] = f2bf(fb.x); u[5] = f2bf(fb.y); u[6] = f2bf(fb.z); u[7] = f2bf(fb.w);
    *reinterpret_cast<uint4*>(&As[buf][(size_t)tid * 8]) = *reinterpret_cast<const uint4*>(u);
  };

  loadA(0, p0a, p0b); issueB(0, 0);
  loadA(1, p1a, p1b); issueB(1, 1);
  wait_vm10();
  __builtin_amdgcn_sched_barrier(0);
  writeA(0, p0a, p0b);

  f32x4 acc[4][4] = {};

  auto body = [&](int k, int b, float4& nxtA, float4& nxtB,
                  const float4& curA, const float4& curB) {
    if (k < NS - 1) wait_vm6(); else wait_vm0();
    __builtin_amdgcn_sched_barrier(0);
    wait_lgkm0();
    __builtin_amdgcn_sched_barrier(0);
    __builtin_amdgcn_s_barrier();
    __builtin_amdgcn_sched_barrier(0);
    bf16x8 af[4], bfr[4];
#pragma unroll
    for (int m = 0; m < 4; ++m)
      af[m] = *reinterpret_cast<const bf16x8*>(&As[b][(m * 16 + lr) * 32 + lg * 8]);
#pragma unroll
    for (int n = 0; n < 4; ++n)
      bfr[n] = *reinterpret_cast<const bf16x8*>(&Bs[b][(wid * 64 + n * 16 + lr) * 32 + lg * 8]);
    __builtin_amdgcn_sched_barrier(0);
    wait_lgkm0();
    __builtin_amdgcn_sched_barrier(0);
    __builtin_amdgcn_s_barrier();
    __builtin_amdgcn_sched_barrier(0);
    if (k + 2 < NS) { loadA(k + 2, nxtA, nxtB); issueB(k + 2, b); }
    __builtin_amdgcn_sched_barrier(0);
    if (k + 1 < NS) {
      if (k + 2 < NS) wait_vm10(); else wait_vm4();
      __builtin_amdgcn_sched_barrier(0);
      writeA(b ^ 1, curA, curB);
    }
    __builtin_amdgcn_sched_barrier(0);
#pragma unroll
    for (int m = 0; m < 4; ++m)
#pragma unroll
      for (int n = 0; n < 4; ++n)
        acc[m][n] = __builtin_amdgcn_mfma_f32_16x16x32_bf16(af[m], bfr[n], acc[m][n], 0, 0, 0);
  };

  for (int k = 0; k < NS; k += 2) {
    body(k, 0, p0a, p0b, p1a, p1b);
    if (k + 1 < NS) body(k + 1, 1, p1a, p1b, p0a, p0b);
  }

#pragma unroll
  for (int m = 0; m < 4; ++m)
#pragma unroll
    for (int r = 0; r < 4; ++r) {
      int grow = m0 + m * 16 + lg * 4 + r;
      float ds = dis[grow];
#pragma unroll
      for (int n = 0; n < 4; ++n) {
        int gcol = wid * 64 + n * 16 + lr;
        C[(size_t)grow * H_DIM + gcol] = f2bf(ds * acc[m][n][r]);
      }
    }
}

// ---------------- layer-2 MFMA GEMM (bf16 A): 2-deep counted-vmcnt pipe ---
template <int KB>
__global__ __launch_bounds__(256) void k_mmB(const u16* __restrict__ A,
                                             const u16* __restrict__ BT,
                                             const float* __restrict__ dis,
                                             u16* __restrict__ C) {
  constexpr int NS = KB >> 5;
  __shared__ __align__(16) u16 As[2][64 * 32];
  __shared__ __align__(16) u16 Bs[2][256 * 32];
  const int tid = threadIdx.x;
  const int lane = tid & 63, wid = tid >> 6;
  const int lr = lane & 15, lg = lane >> 4;
  const int m0 = blockIdx.x * 64;
  const int sseg = (((lane & 3) ^ ((lane >> 3) & 3)) << 3);
  const int arow = tid >> 2;
  const int brow = lane >> 2;
  const int rs8 = ((lg ^ ((lr >> 1) & 3)) << 3);

  auto stage = [&](int s, int b) {
    int k0 = s << 5;
    gl_lds16(A + (size_t)(m0 + arow) * KB + k0 + sseg, (char*)As[b] + wid * 1024);
#pragma unroll
    for (int j = 0; j < 4; ++j) {
      int c = wid * 4 + j;
      gl_lds16(BT + (size_t)(c * 16 + brow) * KB + k0 + sseg, (char*)Bs[b] + c * 1024);
    }
  };

  stage(0, 0);
  stage(1, 1);

  f32x4 acc[4][4] = {};
  for (int k = 0; k < NS; ++k) {
    const int b = k & 1;
    if (k + 1 < NS) wait_vm5(); else wait_vm0();
    __builtin_amdgcn_sched_barrier(0);
    __builtin_amdgcn_s_barrier();
    __builtin_amdgcn_sched_barrier(0);
    bf16x8 af[4], bfr[4];
#pragma unroll
    for (int m = 0; m < 4; ++m)
      af[m] = *reinterpret_cast<const bf16x8*>(&As[b][(m * 16 + lr) * 32 + rs8]);
#pragma unroll
    for (int n = 0; n < 4; ++n)
      bfr[n] = *reinterpret_cast<const bf16x8*>(&Bs[b][(wid * 64 + n * 16 + lr) * 32 + rs8]);
    __builtin_amdgcn_sched_barrier(0);
    wait_lgkm0();
    __builtin_amdgcn_sched_barrier(0);
    __builtin_amdgcn_s_barrier();
    __builtin_amdgcn_sched_barrier(0);
    if (k + 2 < NS) stage(k + 2, b);
    __builtin_amdgcn_sched_barrier(0);
#pragma unroll
    for (int m = 0; m < 4; ++m)
#pragma unroll
      for (int n = 0; n < 4; ++n)
        acc[m][n] = __builtin_amdgcn_mfma_f32_16x16x32_bf16(af[m], bfr[n], acc[m][n], 0, 0, 0);
  }

#pragma unroll
  for (int m = 0; m < 4; ++m)
#pragma unroll
    for (int r = 0; r < 4; ++r) {
      int grow = m0 + m * 16 + lg * 4 + r;
      float ds = dis[grow];
#pragma unroll
      for (int n = 0; n < 4; ++n) {
        int gcol = wid * 64 + n * 16 + lr;
        C[(size_t)grow * H_DIM + gcol] = f2bf(ds * acc[m][n][r]);
      }
    }
}

// ------- paired gather: P wave-loads cover 2P edges (half-wave per edge) --
// h = lane>>5 selects even/odd edge of each pair; c8 = (lane&31)*8 features.
template <int P>
__device__ __forceinline__ void gathp(const u16* __restrict__ t,
                                      const int* __restrict__ csr, int e,
                                      int h, int c8, float* a) {
  int s[P];
  uint4 v[P];
#pragma unroll
  for (int i = 0; i < P; ++i) s[i] = csr[e + 2 * i + h];
#pragma unroll
  for (int i = 0; i < P; ++i)
    v[i] = *reinterpret_cast<const uint4*>(t + ((size_t)s[i] << 8) + c8);
#pragma unroll
  for (int i = 0; i < P; ++i) {
    a[0] += bflo(v[i].x); a[1] += bfhi(v[i].x);
    a[2] += bflo(v[i].y); a[3] += bfhi(v[i].y);
    a[4] += bflo(v[i].z); a[5] += bfhi(v[i].z);
    a[6] += bflo(v[i].w); a[7] += bfhi(v[i].w);
  }
}

// ------- aggregation on pre-scaled rows: h[d] = relu(dd*(sum t'[s] + t'[d]) + b)
// one wave per node; TWO edges per wave-load (1024B/instr). lane = 8 feats.
// FUSE_T3: dot f32 h-row with W3 -> t3' (skips writing h).
template <bool FUSE_T3>
__global__ __launch_bounds__(256) void k_agg(const u16* __restrict__ t,
                                             const int* __restrict__ off,
                                             const int* __restrict__ csr,
                                             const float* __restrict__ dis,
                                             const float* __restrict__ bias,
                                             u16* __restrict__ h,
                                             const float* __restrict__ W3,
                                             float* __restrict__ t3, int N) {
  int wid = threadIdx.x >> 6, lane = threadIdx.x & 63;
  int d = blockIdx.x * 4 + wid;
  if (d >= N) return;
  const int hh = lane >> 5;          // 0: even edges, 1: odd edges
  const int c8 = (lane & 31) * 8;    // element offset of this lane's 8 feats
  float a[8] = {0.f, 0.f, 0.f, 0.f, 0.f, 0.f, 0.f, 0.f};
  int e = off[d], e1 = off[d + 1];
  while (e + 16 <= e1) { gathp<8>(t, csr, e, hh, c8, a); e += 16; }
  if (e + 8 <= e1) { gathp<4>(t, csr, e, hh, c8, a); e += 8; }
  if (e + 4 <= e1) { gathp<2>(t, csr, e, hh, c8, a); e += 4; }
  if (e + 2 <= e1) { gathp<1>(t, csr, e, hh, c8, a); e += 2; }
  if (lane < 32) {
    // odd-edge tail + self row, low half only (exactly-once contributions)
    if (e < e1) {
      uint4 v = *reinterpret_cast<const uint4*>(t + ((size_t)csr[e] << 8) + c8);
      a[0] += bflo(v.x); a[1] += bfhi(v.x); a[2] += bflo(v.y); a[3] += bfhi(v.y);
      a[4] += bflo(v.z); a[5] += bfhi(v.z); a[6] += bflo(v.w); a[7] += bfhi(v.w);
    }
    uint4 sv = *reinterpret_cast<const uint4*>(t + ((size_t)d << 8) + c8);
    a[0] += bflo(sv.x); a[1] += bfhi(sv.x); a[2] += bflo(sv.y); a[3] += bfhi(sv.y);
    a[4] += bflo(sv.z); a[5] += bfhi(sv.z); a[6] += bflo(sv.w); a[7] += bfhi(sv.w);
  }
  // combine halves: every lane ends with the full sum for its 8 features
#pragma unroll
  for (int j = 0; j < 8; ++j) a[j] += __shfl_xor(a[j], 32);
  float dd = dis[d];
  float4 bv0 = *reinterpret_cast<const float4*>(bias + c8);
  float4 bv1 = *reinterpret_cast<const float4*>(bias + c8 + 4);
  float r[8];
  r[0] = fmaxf(dd * a[0] + bv0.x, 0.f); r[1] = fmaxf(dd * a[1] + bv0.y, 0.f);
  r[2] = fmaxf(dd * a[2] + bv0.z, 0.f); r[3] = fmaxf(dd * a[3] + bv0.w, 0.f);
  r[4] = fmaxf(dd * a[4] + bv1.x, 0.f); r[5] = fmaxf(dd * a[5] + bv1.y, 0.f);
  r[6] = fmaxf(dd * a[6] + bv1.z, 0.f); r[7] = fmaxf(dd * a[7] + bv1.w, 0.f);
  if (FUSE_T3) {
    float p0 = 0.f, p1 = 0.f;
#pragma unroll
    for (int j = 0; j < 8; ++j) {
      p0 += r[j] * W3[(c8 + j) * 2];
      p1 += r[j] * W3[(c8 + j) * 2 + 1];
    }
    // reduce across the 32-lane group (both halves hold identical values)
#pragma unroll
    for (int o = 16; o; o >>= 1) { p0 += __shfl_xor(p0, o); p1 += __shfl_xor(p1, o); }
    if (lane == 0) {
      t3[d * 2] = dd * p0;
      t3[d * 2 + 1] = dd * p1;
    }
  } else {
    if (lane < 32) {
      uint4 o;
      o.x = (uint32_t)f2bf(r[0]) | ((uint32_t)f2bf(r[1]) << 16);
      o.y = (uint32_t)f2bf(r[2]) | ((uint32_t)f2bf(r[3]) << 16);
      o.z = (uint32_t)f2bf(r[4]) | ((uint32_t)f2bf(r[5]) << 16);
      o.w = (uint32_t)f2bf(r[6]) | ((uint32_t)f2bf(r[7]) << 16);
      *reinterpret_cast<uint4*>(h + ((size_t)d << 8) + c8) = o;
    }
  }
}

// ------ fused layer-3 aggregation + mean pool: one block per graph --------
__global__ __launch_bounds__(448) void k_aggpool3(const float* __restrict__ t3,
                                                  const int* __restrict__ off,
                                                  const int* __restrict__ csr,
                                                  const float* __restrict__ dis,
                                                  const float* __restrict__ b3,
                                                  float* __restrict__ out) {
  int g = blockIdx.x, t = threadIdx.x;
  int lane = t & 63, wv = t >> 6;
  float a0 = 0.f, a1 = 0.f;
  if (t < NODES_PER_GRAPH) {
    int d = g * NODES_PER_GRAPH + t;
    a0 = t3[d * 2]; a1 = t3[d * 2 + 1];
    int e = off[d], e1 = off[d + 1];
    while (e + 4 <= e1) {
      int s0 = csr[e], s1 = csr[e + 1], s2 = csr[e + 2], s3 = csr[e + 3];
      float2 v0 = *reinterpret_cast<const float2*>(t3 + s0 * 2);
      float2 v1 = *reinterpret_cast<const float2*>(t3 + s1 * 2);
      float2 v2 = *reinterpret_cast<const float2*>(t3 + s2 * 2);
      float2 v3 = *reinterpret_cast<const float2*>(t3 + s3 * 2);
      a0 += v0.x + v1.x + v2.x + v3.x;
      a1 += v0.y + v1.y + v2.y + v3.y;
      e += 4;
    }
    while (e < e1) {
      float2 v = *reinterpret_cast<const float2*>(t3 + csr[e] * 2);
      a0 += v.x; a1 += v.y; ++e;
    }
    float dd = dis[d];
    a0 *= dd; a1 *= dd;
  }
#pragma unroll
  for (int o = 32; o; o >>= 1) { a0 += __shfl_xor(a0, o); a1 += __shfl_xor(a1, o); }
  __shared__ float w0[8], w1[8];
  if (lane == 0) { w0[wv] = a0; w1[wv] = a1; }
  __syncthreads();
  if (t == 0) {
    float s0 = 0.f, s1 = 0.f;
#pragma unroll
    for (int i = 0; i < 7; ++i) { s0 += w0[i]; s1 += w1[i]; }
    out[g * 2]     = s0 * (1.0f / NODES_PER_GRAPH) + b3[0];
    out[g * 2 + 1] = s1 * (1.0f / NODES_PER_GRAPH) + b3[1];
  }
}

extern "C" void kernel_launch(void* const* d_in, const int* in_sizes, int n_in,
                              void* d_out, int out_size, void* d_ws, size_t ws_size,
                              hipStream_t stream) {
  const float* x  = (const float*)d_in[0];
  const int*   ei = (const int*)d_in[1];
  const float* W1 = (const float*)d_in[2];
  const float* b1 = (const float*)d_in[3];
  const float* W2 = (const float*)d_in[4];
  const float* b2 = (const float*)d_in[5];
  const float* W3 = (const float*)d_in[6];
  const float* b3 = (const float*)d_in[7];
  float* out = (float*)d_out;
  const int N = N_NODES, E = N_EDGES;
  const int* src = ei;
  const int* dst = ei + E;

  char* ws = (char*)d_ws;
  size_t o = 0;
  auto alloc = [&](size_t bytes) -> void* {
    void* p = ws + o;
    o += (bytes + 255) & ~(size_t)255;
    return p;
  };
  u16* tA     = (u16*)alloc((size_t)N * H_DIM * 2);
  u16* tB     = (u16*)alloc((size_t)N * H_DIM * 2);
  u16* W1T    = (u16*)alloc((size_t)H_DIM * K1PAD * 2);
  u16* W2T    = (u16*)alloc((size_t)H_DIM * H_DIM * 2);
  float* dis  = (float*)alloc((size_t)N * 4);
  int* counts = (int*)alloc((size_t)N * 4);
  int* cursor = (int*)alloc((size_t)N * 4);
  int* csroff = (int*)alloc((size_t)(N + 1) * 4);
  int* csr    = (int*)alloc((size_t)E * 4);
  float* t3   = (float*)alloc((size_t)N * 2 * 4);
  int* bsum   = (int*)alloc((size_t)NB_SCAN * 4);
  int* boff   = (int*)alloc((size_t)NB_SCAN * 4);

  hipMemsetAsync(counts, 0, (size_t)N * 4, stream);
  k_hist<<<(E + 255) / 256, 256, 0, stream>>>(dst, counts, E);
  k_reduce<<<NB_SCAN, 256, 0, stream>>>(counts, bsum);
  k_scantop<<<1, 256, 0, stream>>>(bsum, boff, csroff + N);
  k_scanlocal<<<NB_SCAN, 256, 0, stream>>>(counts, boff, csroff, cursor, dis);
  k_scatter<<<(E + 255) / 256, 256, 0, stream>>>(src, dst, cursor, csr, E);
  k_prepw<<<K1PAD + H_DIM, 256, 0, stream>>>(W1, W2, W1T, W2T);

  // layer 1
  k_mmA<<<N / 64, 256, 0, stream>>>(x, W1T, dis, tA);
  k_agg<false><<<N / 4, 256, 0, stream>>>(tA, csroff, csr, dis, b1, tB, nullptr, nullptr, N);
  // layer 2 (agg fused with layer-3 matmul -> t3)
  k_mmB<H_DIM><<<N / 64, 256, 0, stream>>>(tB, W2T, dis, tA);
  k_agg<true><<<N / 4, 256, 0, stream>>>(tA, csroff, csr, dis, b2, nullptr, W3, t3, N);
  // layer 3 aggregation fused with mean pool
  k_aggpool3<<<N_GRAPHS, 448, 0, stream>>>(t3, csroff, csr, dis, b3, out);
}

// Round 9
// 265.272 us; speedup vs baseline: 1.0908x; 1.0908x over previous
//
#include <hip/hip_runtime.h>
#include <hip/hip_bf16.h>
#include <stdint.h>

typedef __attribute__((ext_vector_type(8))) __bf16 bf16x8;
typedef __attribute__((ext_vector_type(4))) float f32x4;
typedef unsigned short u16;

#define N_NODES 51200
#define N_EDGES 819200
#define F_IN 400
#define K1PAD 416
#define H_DIM 256
#define C_OUT 2
#define N_GRAPHS 128
#define NODES_PER_GRAPH 400
#define NB_SCAN (N_NODES / 256)   // 200 blocks

__device__ __forceinline__ u16 f2bf(float f) {
  uint32_t u = __builtin_bit_cast(uint32_t, f);
  u = (u + 0x7fffu + ((u >> 16) & 1u)) >> 16;
  return (u16)u;
}
__device__ __forceinline__ float bf2f(u16 s) {
  uint32_t u = ((uint32_t)s) << 16;
  return __builtin_bit_cast(float, u);
}

typedef const __attribute__((address_space(1))) unsigned int* gas_ptr;
typedef __attribute__((address_space(3))) unsigned int* las_ptr;
__device__ __forceinline__ void gl_lds16(const void* g, void* l) {
  __builtin_amdgcn_global_load_lds((gas_ptr)g, (las_ptr)l, 16, 0, 0);
}
__device__ __forceinline__ void wait_vm0()   { asm volatile("s_waitcnt vmcnt(0)" ::: "memory"); }
__device__ __forceinline__ void wait_vm4()   { asm volatile("s_waitcnt vmcnt(4)" ::: "memory"); }
__device__ __forceinline__ void wait_vm5()   { asm volatile("s_waitcnt vmcnt(5)" ::: "memory"); }
__device__ __forceinline__ void wait_vm6()   { asm volatile("s_waitcnt vmcnt(6)" ::: "memory"); }
__device__ __forceinline__ void wait_vm10()  { asm volatile("s_waitcnt vmcnt(10)" ::: "memory"); }
__device__ __forceinline__ void wait_lgkm0() { asm volatile("s_waitcnt lgkmcnt(0)" ::: "memory"); }

// ---------------- degree histogram (counts[d] = in-degree) ----------------
__global__ void k_hist(const int* __restrict__ dst, int* __restrict__ counts, int E) {
  int e = blockIdx.x * 256 + threadIdx.x;
  if (e < E) atomicAdd(&counts[dst[e]], 1);
}

// ---------------- hierarchical scan: phase 1, per-block sums --------------
__global__ __launch_bounds__(256) void k_reduce(const int* __restrict__ counts,
                                                int* __restrict__ bsum) {
  int i = blockIdx.x * 256 + threadIdx.x;
  int v = counts[i];
#pragma unroll
  for (int o = 32; o; o >>= 1) v += __shfl_xor(v, o);
  __shared__ int wsum[4];
  if ((threadIdx.x & 63) == 0) wsum[threadIdx.x >> 6] = v;
  __syncthreads();
  if (threadIdx.x == 0) bsum[blockIdx.x] = wsum[0] + wsum[1] + wsum[2] + wsum[3];
}

// ---------------- phase 2: scan the 200 block sums (one small block) ------
__global__ __launch_bounds__(256) void k_scantop(const int* __restrict__ bsum,
                                                 int* __restrict__ boff,
                                                 int* __restrict__ off_last) {
  __shared__ int s[256];
  int t = threadIdx.x;
  int v = (t < NB_SCAN) ? bsum[t] : 0;
  s[t] = v;
  __syncthreads();
  for (int d = 1; d < 256; d <<= 1) {
    int u = (t >= d) ? s[t - d] : 0;
    __syncthreads();
    s[t] += u;
    __syncthreads();
  }
  if (t < NB_SCAN) boff[t] = s[t] - v;   // exclusive prefix of block sums
  if (t == 0) *off_last = N_EDGES;       // off[N] = total edges
}

// ---------------- phase 3: local scan + block offset; also dis ------------
__global__ __launch_bounds__(256) void k_scanlocal(const int* __restrict__ counts,
                                                   const int* __restrict__ boff,
                                                   int* __restrict__ off,
                                                   int* __restrict__ cursor,
                                                   float* __restrict__ dis) {
  __shared__ int s[256];
  int t = threadIdx.x;
  int i = blockIdx.x * 256 + t;
  int v = counts[i];
  s[t] = v;
  __syncthreads();
  for (int d = 1; d < 256; d <<= 1) {
    int u = (t >= d) ? s[t - d] : 0;
    __syncthreads();
    s[t] += u;
    __syncthreads();
  }
  int ex = boff[blockIdx.x] + s[t] - v;
  off[i] = ex;
  cursor[i] = ex;
  dis[i] = rsqrtf(1.0f + (float)v);
}

// ---------------- scatter edges into CSR (sorted by dst) ------------------
__global__ void k_scatter(const int* __restrict__ src, const int* __restrict__ dst,
                          int* __restrict__ cursor, int* __restrict__ csr_src, int E) {
  int e = blockIdx.x * 256 + threadIdx.x;
  if (e < E) {
    int d = dst[e];
    int p = atomicAdd(&cursor[d], 1);
    csr_src[p] = src[e];
  }
}

// ------- transpose weights to bf16 [n][k], K1 padded to 416 with zeros ----
__global__ __launch_bounds__(256) void k_prepw(const float* __restrict__ W1,
                                               const float* __restrict__ W2,
                                               u16* __restrict__ W1T,
                                               u16* __restrict__ W2T) {
  int b = blockIdx.x, n = threadIdx.x;
  if (b < K1PAD) {
    int k = b;
    W1T[n * K1PAD + k] = (k < F_IN) ? f2bf(W1[k * H_DIM + n]) : (u16)0;
  } else {
    int k = b - K1PAD;
    W2T[n * H_DIM + k] = f2bf(W2[k * H_DIM + n]);
  }
}

// ---- shared epilogue idea: per-(row, 64-col wave quadrant) int8 quant ----
// q = rint(acc * 127/segmax); rs4[row*4+wid] = dis[row]*segmax/127
// (dis cancels out of q, folds into the scale)

// ---------------- layer-1 MFMA GEMM (fp32 A): 2-deep counted-vmcnt pipe ---
__global__ __launch_bounds__(256) void k_mmA(const float* __restrict__ Ap,
                                             const u16* __restrict__ BT,
                                             const float* __restrict__ dis,
                                             int8_t* __restrict__ Cq,
                                             float* __restrict__ rs4) {
  constexpr int K = F_IN, KB = K1PAD, NS = KB >> 5;   // NS = 13
  __shared__ __align__(16) u16 As[2][64 * 32];
  __shared__ __align__(16) u16 Bs[2][256 * 32];
  const int tid = threadIdx.x;
  const int lane = tid & 63, wid = tid >> 6;
  const int lr = lane & 15, lg = lane >> 4;
  const int m0 = blockIdx.x * 64;
  const int bRow = lane >> 2, bK8 = (lane & 3) << 3;
  const int aRow = tid >> 2, aK8 = (tid & 3) << 3;

  float4 p0a, p0b, p1a, p1b;

  auto issueB = [&](int s, int buf) {
    int k0 = s << 5;
#pragma unroll
    for (int j = 0; j < 4; ++j) {
      int c = wid * 4 + j;
      gl_lds16(BT + (size_t)(c * 16 + bRow) * KB + k0 + bK8, (char*)Bs[buf] + c * 1024);
    }
  };
  auto loadA = [&](int s, float4& fa, float4& fb) {
    int gk = (s << 5) + aK8;
    const float* p = Ap + (size_t)(m0 + aRow) * K + gk;
    if (gk < K) {
      fa = *reinterpret_cast<const float4*>(p);
      fb = *reinterpret_cast<const float4*>(p + 4);
    } else {
      fa = float4{0.f, 0.f, 0.f, 0.f};
      fb = float4{0.f, 0.f, 0.f, 0.f};
    }
  };
  auto writeA = [&](int buf, const float4& fa, const float4& fb) {
    alignas(16) u16 u[8];
    u[0] = f2bf(fa.x); u[1] = f2bf(fa.y); u[2] = f2bf(fa.z); u[3] = f2bf(fa.w);
    u[4] = f2bf(fb.x); u[5] = f2bf(fb.y); u[6] = f2bf(fb.z); u[7] = f2bf(fb.w);
    *reinterpret_cast<uint4*>(&As[buf][(size_t)tid * 8]) = *reinterpret_cast<const uint4*>(u);
  };

  loadA(0, p0a, p0b); issueB(0, 0);
  loadA(1, p1a, p1b); issueB(1, 1);
  wait_vm10();
  __builtin_amdgcn_sched_barrier(0);
  writeA(0, p0a, p0b);

  f32x4 acc[4][4] = {};

  auto body = [&](int k, int b, float4& nxtA, float4& nxtB,
                  const float4& curA, const float4& curB) {
    if (k < NS - 1) wait_vm6(); else wait_vm0();
    __builtin_amdgcn_sched_barrier(0);
    wait_lgkm0();
    __builtin_amdgcn_sched_barrier(0);
    __builtin_amdgcn_s_barrier();
    __builtin_amdgcn_sched_barrier(0);
    bf16x8 af[4], bfr[4];
#pragma unroll
    for (int m = 0; m < 4; ++m)
      af[m] = *reinterpret_cast<const bf16x8*>(&As[b][(m * 16 + lr) * 32 + lg * 8]);
#pragma unroll
    for (int n = 0; n < 4; ++n)
      bfr[n] = *reinterpret_cast<const bf16x8*>(&Bs[b][(wid * 64 + n * 16 + lr) * 32 + lg * 8]);
    __builtin_amdgcn_sched_barrier(0);
    wait_lgkm0();
    __builtin_amdgcn_sched_barrier(0);
    __builtin_amdgcn_s_barrier();
    __builtin_amdgcn_sched_barrier(0);
    if (k + 2 < NS) { loadA(k + 2, nxtA, nxtB); issueB(k + 2, b); }
    __builtin_amdgcn_sched_barrier(0);
    if (k + 1 < NS) {
      if (k + 2 < NS) wait_vm10(); else wait_vm4();
      __builtin_amdgcn_sched_barrier(0);
      writeA(b ^ 1, curA, curB);
    }
    __builtin_amdgcn_sched_barrier(0);
#pragma unroll
    for (int m = 0; m < 4; ++m)
#pragma unroll
      for (int n = 0; n < 4; ++n)
        acc[m][n] = __builtin_amdgcn_mfma_f32_16x16x32_bf16(af[m], bfr[n], acc[m][n], 0, 0, 0);
  };

  for (int k = 0; k < NS; k += 2) {
    body(k, 0, p0a, p0b, p1a, p1b);
    if (k + 1 < NS) body(k + 1, 1, p1a, p1b, p0a, p0b);
  }

  // ---- epilogue: per-quadrant int8 quantization
  float pam[4][4];
#pragma unroll
  for (int m = 0; m < 4; ++m)
#pragma unroll
    for (int r = 0; r < 4; ++r) {
      float v0 = fabsf(acc[m][0][r]), v1 = fabsf(acc[m][1][r]);
      float v2 = fabsf(acc[m][2][r]), v3 = fabsf(acc[m][3][r]);
      pam[m][r] = fmaxf(fmaxf(v0, v1), fmaxf(v2, v3));
    }
#pragma unroll
  for (int o = 1; o < 16; o <<= 1)
#pragma unroll
    for (int m = 0; m < 4; ++m)
#pragma unroll
      for (int r = 0; r < 4; ++r)
        pam[m][r] = fmaxf(pam[m][r], __shfl_xor(pam[m][r], o));
#pragma unroll
  for (int m = 0; m < 4; ++m)
#pragma unroll
    for (int r = 0; r < 4; ++r) {
      int row = m * 16 + lg * 4 + r;
      int grow = m0 + row;
      float fm = fmaxf(pam[m][r], 1e-20f);
      float inv = 127.0f / fm;
      if (lr == 0) rs4[(size_t)grow * 4 + wid] = dis[grow] * fm * (1.0f / 127.0f);
#pragma unroll
      for (int n = 0; n < 4; ++n) {
        int q = (int)rintf(acc[m][n][r] * inv);
        Cq[(size_t)grow * H_DIM + wid * 64 + n * 16 + lr] = (int8_t)q;
      }
    }
}

// ---------------- layer-2 MFMA GEMM (bf16 A): 2-deep counted-vmcnt pipe ---
template <int KB>
__global__ __launch_bounds__(256) void k_mmB(const u16* __restrict__ A,
                                             const u16* __restrict__ BT,
                                             const float* __restrict__ dis,
                                             int8_t* __restrict__ Cq,
                                             float* __restrict__ rs4) {
  constexpr int NS = KB >> 5;
  __shared__ __align__(16) u16 As[2][64 * 32];
  __shared__ __align__(16) u16 Bs[2][256 * 32];
  const int tid = threadIdx.x;
  const int lane = tid & 63, wid = tid >> 6;
  const int lr = lane & 15, lg = lane >> 4;
  const int m0 = blockIdx.x * 64;
  const int sseg = (((lane & 3) ^ ((lane >> 3) & 3)) << 3);
  const int arow = tid >> 2;
  const int brow = lane >> 2;
  const int rs8 = ((lg ^ ((lr >> 1) & 3)) << 3);

  auto stage = [&](int s, int b) {
    int k0 = s << 5;
    gl_lds16(A + (size_t)(m0 + arow) * KB + k0 + sseg, (char*)As[b] + wid * 1024);
#pragma unroll
    for (int j = 0; j < 4; ++j) {
      int c = wid * 4 + j;
      gl_lds16(BT + (size_t)(c * 16 + brow) * KB + k0 + sseg, (char*)Bs[b] + c * 1024);
    }
  };

  stage(0, 0);
  stage(1, 1);

  f32x4 acc[4][4] = {};
  for (int k = 0; k < NS; ++k) {
    const int b = k & 1;
    if (k + 1 < NS) wait_vm5(); else wait_vm0();
    __builtin_amdgcn_sched_barrier(0);
    __builtin_amdgcn_s_barrier();
    __builtin_amdgcn_sched_barrier(0);
    bf16x8 af[4], bfr[4];
#pragma unroll
    for (int m = 0; m < 4; ++m)
      af[m] = *reinterpret_cast<const bf16x8*>(&As[b][(m * 16 + lr) * 32 + rs8]);
#pragma unroll
    for (int n = 0; n < 4; ++n)
      bfr[n] = *reinterpret_cast<const bf16x8*>(&Bs[b][(wid * 64 + n * 16 + lr) * 32 + rs8]);
    __builtin_amdgcn_sched_barrier(0);
    wait_lgkm0();
    __builtin_amdgcn_sched_barrier(0);
    __builtin_amdgcn_s_barrier();
    __builtin_amdgcn_sched_barrier(0);
    if (k + 2 < NS) stage(k + 2, b);
    __builtin_amdgcn_sched_barrier(0);
#pragma unroll
    for (int m = 0; m < 4; ++m)
#pragma unroll
      for (int n = 0; n < 4; ++n)
        acc[m][n] = __builtin_amdgcn_mfma_f32_16x16x32_bf16(af[m], bfr[n], acc[m][n], 0, 0, 0);
  }

  // ---- epilogue: per-quadrant int8 quantization
  float pam[4][4];
#pragma unroll
  for (int m = 0; m < 4; ++m)
#pragma unroll
    for (int r = 0; r < 4; ++r) {
      float v0 = fabsf(acc[m][0][r]), v1 = fabsf(acc[m][1][r]);
      float v2 = fabsf(acc[m][2][r]), v3 = fabsf(acc[m][3][r]);
      pam[m][r] = fmaxf(fmaxf(v0, v1), fmaxf(v2, v3));
    }
#pragma unroll
  for (int o = 1; o < 16; o <<= 1)
#pragma unroll
    for (int m = 0; m < 4; ++m)
#pragma unroll
      for (int r = 0; r < 4; ++r)
        pam[m][r] = fmaxf(pam[m][r], __shfl_xor(pam[m][r], o));
#pragma unroll
  for (int m = 0; m < 4; ++m)
#pragma unroll
    for (int r = 0; r < 4; ++r) {
      int row = m * 16 + lg * 4 + r;
      int grow = m0 + row;
      float fm = fmaxf(pam[m][r], 1e-20f);
      float inv = 127.0f / fm;
      if (lr == 0) rs4[(size_t)grow * 4 + wid] = dis[grow] * fm * (1.0f / 127.0f);
#pragma unroll
      for (int n = 0; n < 4; ++n) {
        int q = (int)rintf(acc[m][n][r] * inv);
        Cq[(size_t)grow * H_DIM + wid * 64 + n * 16 + lr] = (int8_t)q;
      }
    }
}

// ------- int8 gather group: U independent row loads + quadrant scales -----
template <int U>
__device__ __forceinline__ void gath8(const int8_t* __restrict__ tq,
                                      const float* __restrict__ rs4,
                                      const int* __restrict__ csr, int e,
                                      int f0, int qo,
                                      float& a0, float& a1, float& a2, float& a3) {
  int s[U];
  uint32_t v[U];
  float sc[U];
#pragma unroll
  for (int i = 0; i < U; ++i) s[i] = csr[e + i];
#pragma unroll
  for (int i = 0; i < U; ++i) {
    v[i] = *reinterpret_cast<const uint32_t*>(tq + ((size_t)s[i] << 8) + f0);
    sc[i] = rs4[((size_t)s[i] << 2) + qo];
  }
#pragma unroll
  for (int i = 0; i < U; ++i) {
    a0 += sc[i] * (float)(int8_t)(v[i]);
    a1 += sc[i] * (float)(int8_t)(v[i] >> 8);
    a2 += sc[i] * (float)(int8_t)(v[i] >> 16);
    a3 += sc[i] * (float)(int8_t)(v[i] >> 24);
  }
}

// ------- aggregation on quantized pre-scaled rows ------------------------
// h[d] = relu(dd*(sum t'[s] + t'[d]) + b); t'[s] = rs4[s][quad] * q[s]
// one wave per node, lane = 4 features. FUSE_T3: dot f32 h-row with W3 -> t3'.
template <bool FUSE_T3>
__global__ __launch_bounds__(256) void k_agg(const int8_t* __restrict__ tq,
                                             const float* __restrict__ rs4,
                                             const int* __restrict__ off,
                                             const int* __restrict__ csr,
                                             const float* __restrict__ dis,
                                             const float* __restrict__ bias,
                                             u16* __restrict__ h,
                                             const float* __restrict__ W3,
                                             float* __restrict__ t3, int N) {
  int wid = threadIdx.x >> 6, lane = threadIdx.x & 63;
  int d = blockIdx.x * 4 + wid;
  if (d >= N) return;
  int f0 = lane * 4;
  int qo = lane >> 4;
  float a0, a1, a2, a3;
  {
    uint32_t v = *reinterpret_cast<const uint32_t*>(tq + ((size_t)d << 8) + f0);
    float sc = rs4[((size_t)d << 2) + qo];
    a0 = sc * (float)(int8_t)(v);
    a1 = sc * (float)(int8_t)(v >> 8);
    a2 = sc * (float)(int8_t)(v >> 16);
    a3 = sc * (float)(int8_t)(v >> 24);
  }
  int e = off[d], e1 = off[d + 1];
  while (e + 8 <= e1) { gath8<8>(tq, rs4, csr, e, f0, qo, a0, a1, a2, a3); e += 8; }
  if (e + 4 <= e1) { gath8<4>(tq, rs4, csr, e, f0, qo, a0, a1, a2, a3); e += 4; }
  if (e + 2 <= e1) { gath8<2>(tq, rs4, csr, e, f0, qo, a0, a1, a2, a3); e += 2; }
  if (e < e1)      { gath8<1>(tq, rs4, csr, e, f0, qo, a0, a1, a2, a3); }
  float dd = dis[d];
  float4 bv = *reinterpret_cast<const float4*>(bias + f0);
  float r0 = fmaxf(dd * a0 + bv.x, 0.f);
  float r1 = fmaxf(dd * a1 + bv.y, 0.f);
  float r2 = fmaxf(dd * a2 + bv.z, 0.f);
  float r3 = fmaxf(dd * a3 + bv.w, 0.f);
  if (FUSE_T3) {
    float p0 = r0 * W3[(f0 + 0) * 2]     + r1 * W3[(f0 + 1) * 2]
             + r2 * W3[(f0 + 2) * 2]     + r3 * W3[(f0 + 3) * 2];
    float p1 = r0 * W3[(f0 + 0) * 2 + 1] + r1 * W3[(f0 + 1) * 2 + 1]
             + r2 * W3[(f0 + 2) * 2 + 1] + r3 * W3[(f0 + 3) * 2 + 1];
#pragma unroll
    for (int o = 32; o; o >>= 1) { p0 += __shfl_xor(p0, o); p1 += __shfl_xor(p1, o); }
    if (lane == 0) {
      t3[d * 2] = dd * p0;
      t3[d * 2 + 1] = dd * p1;
    }
  } else {
    ushort4 o;
    o.x = f2bf(r0); o.y = f2bf(r1); o.z = f2bf(r2); o.w = f2bf(r3);
    *reinterpret_cast<ushort4*>(h + ((size_t)d << 8) + f0) = o;
  }
}

// ------ fused layer-3 aggregation + mean pool: one block per graph --------
__global__ __launch_bounds__(448) void k_aggpool3(const float* __restrict__ t3,
                                                  const int* __restrict__ off,
                                                  const int* __restrict__ csr,
                                                  const float* __restrict__ dis,
                                                  const float* __restrict__ b3,
                                                  float* __restrict__ out) {
  int g = blockIdx.x, t = threadIdx.x;
  int lane = t & 63, wv = t >> 6;
  float a0 = 0.f, a1 = 0.f;
  if (t < NODES_PER_GRAPH) {
    int d = g * NODES_PER_GRAPH + t;
    a0 = t3[d * 2]; a1 = t3[d * 2 + 1];
    int e = off[d], e1 = off[d + 1];
    while (e + 4 <= e1) {
      int s0 = csr[e], s1 = csr[e + 1], s2 = csr[e + 2], s3 = csr[e + 3];
      float2 v0 = *reinterpret_cast<const float2*>(t3 + s0 * 2);
      float2 v1 = *reinterpret_cast<const float2*>(t3 + s1 * 2);
      float2 v2 = *reinterpret_cast<const float2*>(t3 + s2 * 2);
      float2 v3 = *reinterpret_cast<const float2*>(t3 + s3 * 2);
      a0 += v0.x + v1.x + v2.x + v3.x;
      a1 += v0.y + v1.y + v2.y + v3.y;
      e += 4;
    }
    while (e < e1) {
      float2 v = *reinterpret_cast<const float2*>(t3 + csr[e] * 2);
      a0 += v.x; a1 += v.y; ++e;
    }
    float dd = dis[d];
    a0 *= dd; a1 *= dd;
  }
#pragma unroll
  for (int o = 32; o; o >>= 1) { a0 += __shfl_xor(a0, o); a1 += __shfl_xor(a1, o); }
  __shared__ float w0[8], w1[8];
  if (lane == 0) { w0[wv] = a0; w1[wv] = a1; }
  __syncthreads();
  if (t == 0) {
    float s0 = 0.f, s1 = 0.f;
#pragma unroll
    for (int i = 0; i < 7; ++i) { s0 += w0[i]; s1 += w1[i]; }
    out[g * 2]     = s0 * (1.0f / NODES_PER_GRAPH) + b3[0];
    out[g * 2 + 1] = s1 * (1.0f / NODES_PER_GRAPH) + b3[1];
  }
}

extern "C" void kernel_launch(void* const* d_in, const int* in_sizes, int n_in,
                              void* d_out, int out_size, void* d_ws, size_t ws_size,
                              hipStream_t stream) {
  const float* x  = (const float*)d_in[0];
  const int*   ei = (const int*)d_in[1];
  const float* W1 = (const float*)d_in[2];
  const float* b1 = (const float*)d_in[3];
  const float* W2 = (const float*)d_in[4];
  const float* b2 = (const float*)d_in[5];
  const float* W3 = (const float*)d_in[6];
  const float* b3 = (const float*)d_in[7];
  float* out = (float*)d_out;
  const int N = N_NODES, E = N_EDGES;
  const int* src = ei;
  const int* dst = ei + E;

  char* ws = (char*)d_ws;
  size_t o = 0;
  auto alloc = [&](size_t bytes) -> void* {
    void* p = ws + o;
    o += (bytes + 255) & ~(size_t)255;
    return p;
  };
  int8_t* tQ  = (int8_t*)alloc((size_t)N * H_DIM);
  float* rs4  = (float*)alloc((size_t)N * 4 * 4);
  u16* tB     = (u16*)alloc((size_t)N * H_DIM * 2);
  u16* W1T    = (u16*)alloc((size_t)H_DIM * K1PAD * 2);
  u16* W2T    = (u16*)alloc((size_t)H_DIM * H_DIM * 2);
  float* dis  = (float*)alloc((size_t)N * 4);
  int* counts = (int*)alloc((size_t)N * 4);
  int* cursor = (int*)alloc((size_t)N * 4);
  int* csroff = (int*)alloc((size_t)(N + 1) * 4);
  int* csr    = (int*)alloc((size_t)E * 4);
  float* t3   = (float*)alloc((size_t)N * 2 * 4);
  int* bsum   = (int*)alloc((size_t)NB_SCAN * 4);
  int* boff   = (int*)alloc((size_t)NB_SCAN * 4);

  hipMemsetAsync(counts, 0, (size_t)N * 4, stream);
  k_hist<<<(E + 255) / 256, 256, 0, stream>>>(dst, counts, E);
  k_reduce<<<NB_SCAN, 256, 0, stream>>>(counts, bsum);
  k_scantop<<<1, 256, 0, stream>>>(bsum, boff, csroff + N);
  k_scanlocal<<<NB_SCAN, 256, 0, stream>>>(counts, boff, csroff, cursor, dis);
  k_scatter<<<(E + 255) / 256, 256, 0, stream>>>(src, dst, cursor, csr, E);
  k_prepw<<<K1PAD + H_DIM, 256, 0, stream>>>(W1, W2, W1T, W2T);

  // layer 1
  k_mmA<<<N / 64, 256, 0, stream>>>(x, W1T, dis, tQ, rs4);
  k_agg<false><<<N / 4, 256, 0, stream>>>(tQ, rs4, csroff, csr, dis, b1, tB, nullptr, nullptr, N);
  // layer 2 (agg fused with layer-3 matmul -> t3)
  k_mmB<H_DIM><<<N / 64, 256, 0, stream>>>(tB, W2T, dis, tQ, rs4);
  k_agg<true><<<N / 4, 256, 0, stream>>>(tQ, rs4, csroff, csr, dis, b2, nullptr, W3, t3, N);
  // layer 3 aggregation fused with mean pool
  k_aggpool3<<<N_GRAPHS, 448, 0, stream>>>(t3, csroff, csr, dis, b3, out);
}